// Round 13
// baseline (278.630 us; speedup 1.0000x reference)
//
#include <hip/hip_runtime.h>
#include <math.h>

#define NN 10000       // nodes per graph
#define NE 160000      // edges per graph
#define DD 512         // feature dim
#define MPAD 20096     // 157 * 128 rows (padded batched M)

typedef __attribute__((ext_vector_type(8))) short bf16x8;
typedef __attribute__((ext_vector_type(4))) float f32x4;
typedef __attribute__((ext_vector_type(8))) unsigned short u16x8;

__device__ __forceinline__ unsigned short f2bf(float f) {
    unsigned u = __float_as_uint(f);
    u += 0x7FFFu + ((u >> 16) & 1u);          // round-to-nearest-even
    return (unsigned short)(u >> 16);
}
__device__ __forceinline__ float bf2f(unsigned short h) {
    return __uint_as_float(((unsigned)h) << 16);
}

// async global->LDS, 16B per lane; LDS dest is wave-uniform base + lane*16
#define GLOAD16(g, l) __builtin_amdgcn_global_load_lds( \
    (const __attribute__((address_space(1))) void*)(unsigned long long)(const void*)(g), \
    (__attribute__((address_space(3))) void*)(unsigned)(unsigned long long)(void*)(l), \
    16, 0, 0)

// ---------------------------------------------------------------------------
// fused preprocessing: [0,5024) cvt_x | [5024,6274) count | [6274,9346) cvt_w
// (the three are mutually independent; one dispatch overlaps them)
#define NB_CVTX 5024   // MPAD*DD/8/256
#define NB_CNT  1250   // 2*NE/256
#define NB_CVTW 3072   // (DD/16)*(DD/16)*3
__global__ __launch_bounds__(256) void k_pre(const float* __restrict__ x1,
                                             const float* __restrict__ x2,
                                             unsigned short* __restrict__ xb,
                                             const int* __restrict__ e1,
                                             const int* __restrict__ e2,
                                             int* __restrict__ cnt,
                                             const float* __restrict__ W1,
                                             const float* __restrict__ W2,
                                             const float* __restrict__ W3,
                                             unsigned short* __restrict__ Wt) {
    int bid = blockIdx.x;
    int tid = threadIdx.x;
    if (bid < NB_CVTX) {
        // ---- fp32 -> bf16 convert of node features, tail rows zeroed ----
        long long i8 = ((long long)bid * 256 + tid) * 8;
        int row = (int)(i8 >> 9);
        int col = (int)(i8 & 511);
        u16x8 ov;
        if (row < 2 * NN) {
            const float* src = (row < NN) ? (x1 + (size_t)row * DD + col)
                                          : (x2 + (size_t)(row - NN) * DD + col);
            float4 f0 = ((const float4*)src)[0];
            float4 f1 = ((const float4*)src)[1];
            ov[0] = f2bf(f0.x); ov[1] = f2bf(f0.y); ov[2] = f2bf(f0.z); ov[3] = f2bf(f0.w);
            ov[4] = f2bf(f1.x); ov[5] = f2bf(f1.y); ov[6] = f2bf(f1.z); ov[7] = f2bf(f1.w);
        } else {
            #pragma unroll
            for (int j = 0; j < 8; ++j) ov[j] = 0;
        }
        *(u16x8*)(xb + i8) = ov;
    } else if (bid < NB_CVTX + NB_CNT) {
        // ---- in-degree count (self-loop handled as +1 later) ----
        int i = (bid - NB_CVTX) * 256 + tid;
        if (i < NE) {
            atomicAdd(&cnt[e1[NE + i]], 1);
        } else {
            int e = i - NE;
            atomicAdd(&cnt[NN + e2[NE + e]], 1);
        }
    } else {
        // ---- W[k][n] fp32 -> Wt[n][k] bf16, 16x16 tiles, 256 threads ----
        __shared__ float t[16][17];
        int b2 = bid - NB_CVTX - NB_CNT;
        int z = b2 >> 10;                 // 0..2
        int rem = b2 & 1023;
        int n0 = (rem & 31) * 16;
        int k0 = (rem >> 5) * 16;
        const float* W = (z == 0) ? W1 : (z == 1) ? W2 : W3;
        unsigned short* o = Wt + (size_t)z * DD * DD;
        int tx = tid & 15, ty = tid >> 4;
        t[ty][tx] = W[(size_t)(k0 + ty) * DD + n0 + tx];
        __syncthreads();
        o[(size_t)(n0 + ty) * DD + k0 + tx] = f2bf(t[tx][ty]);
    }
}

// exclusive scan of per-node edge counts -> CSR offsets; also emits dinv.
// One block per graph.
__global__ void k_scan(const int* cnt, int* offs, float* dinv) {
    int g = blockIdx.x;
    const int* c = cnt + g * NN;
    int* o = offs + g * (NN + 1);
    __shared__ int sums[1024];
    int t = threadIdx.x;                  // 1024 threads
    const int PER = 10;                   // 1024*10 >= NN
    int base = t * PER;
    int vals[PER];
    int local = 0;
    #pragma unroll
    for (int j = 0; j < PER; ++j) {
        int idx = base + j;
        int v = (idx < NN) ? c[idx] : 0;
        vals[j] = v; local += v;
        if (idx < NN) dinv[g * NN + idx] = rsqrtf((float)(v + 1));
    }
    sums[t] = local;
    __syncthreads();
    for (int off = 1; off < 1024; off <<= 1) {
        int v = (t >= off) ? sums[t - off] : 0;
        __syncthreads();
        sums[t] += v;
        __syncthreads();
    }
    int prefix = (t > 0) ? sums[t - 1] : 0;   // exclusive
    #pragma unroll
    for (int j = 0; j < PER; ++j) {
        int idx = base + j;
        if (idx < NN) { o[idx] = prefix; prefix += vals[j]; }
    }
    if (t == 1023) o[NN] = sums[1023];
}

// scatter edges into CSR buckets (adj holds SRC node per incoming edge of dst)
__global__ void k_fill(const int* e1, const int* e2, const int* offs,
                       int* cursor, int* adj) {
    int i = blockIdx.x * blockDim.x + threadIdx.x;
    if (i >= 2 * NE) return;
    int g = (i < NE) ? 0 : 1;
    int e = i - g * NE;
    const int* ei = g ? e2 : e1;
    int s = ei[e];
    int d = ei[NE + e];
    int pos = atomicAdd(&cursor[g * NN + d], 1);
    adj[g * NE + offs[g * (NN + 1) + d] + pos] = s;
}

// ---------------------------------------------------------------------------
// bf16 MFMA GEMM: C[MPAD x 512] = dinv[row] * (A[MPAD x 512] * W^T).
// 128x64 tile -> 1256 blocks (~4.9/CU): inter-block TLP hides the per-K-step
// barrier drain (R12 showed more waves/block does NOT — they share the
// barrier). 4 waves (2x2: wave computes 64x32), 256 threads, 16x16x32 MFMA,
// global_load_lds width-16 (A:2 + B:1 per thread per step). T3 2-phase
// pipeline: BK=32 double-buffered LDS (24 KB), STAGE(next) before
// COMPUTE(cur), ONE barrier per K-step. Epilogue: dinv scale, LDS bounce
// (stride-72 u16), coalesced u16x8 stores. XCD swizzle: 1256%8==0 -> simple
// bijective gi=(b&7)*157+(b>>3); consecutive same-XCD gi share an A row-panel.
__global__ __launch_bounds__(256) void k_gemm(const unsigned short* __restrict__ A,
                                              const unsigned short* __restrict__ Bt,
                                              const float* __restrict__ dinv,
                                              unsigned short* __restrict__ C) {
    __shared__ char smem[24576];          // A0 8K | B0 4K | A1 8K | B1 4K; C-bounce 18.4K
    bf16x8* A0 = (bf16x8*)smem;           // 512 chunks [kb 0..3][row 0..127]
    bf16x8* B0 = (bf16x8*)(smem + 8192);  // 256 chunks [kb 0..3][row 0..63]
    bf16x8* A1 = (bf16x8*)(smem + 12288);
    bf16x8* B1 = (bf16x8*)(smem + 20480);

    int tid = threadIdx.x;
    int lane = tid & 63;
    int wid = tid >> 6;
    int wr = wid >> 1, wc = wid & 1;     // 2 x 2 wave grid (64x32 per wave)

    int b = blockIdx.x;                      // 0..1255
    int gi = (b & 7) * 157 + (b >> 3);       // bijective (1256 = 8*157)
    int rp = gi >> 3, cb = gi & 7;
    int row0 = rp * 128, col0 = cb * 64;

    // staging: A chunks {tid, 256+tid}; B chunk tid (kb=wid, row=lane)
    int chA0 = wid * 64 + lane;
    int chA1 = 256 + wid * 64 + lane;
    const unsigned short* gA0 = A + (size_t)(row0 + (chA0 & 127)) * DD + (chA0 >> 7) * 8;
    const unsigned short* gA1 = A + (size_t)(row0 + (chA1 & 127)) * DD + (chA1 >> 7) * 8;
    const unsigned short* gB0 = Bt + (size_t)(col0 + lane) * DD + wid * 8;

#define STAGE(Ad, Bd) do { \
        GLOAD16(gA0, (Ad) + wid * 64); \
        GLOAD16(gA1, (Ad) + 256 + wid * 64); \
        GLOAD16(gB0, (Bd) + wid * 64); \
        gA0 += 32; gA1 += 32; gB0 += 32; \
    } while (0)

#define COMPUTE(As_, Bs_) do { \
        bf16x8 af[4], bfr[2]; \
        _Pragma("unroll") \
        for (int m = 0; m < 4; ++m) \
            af[m]  = (As_)[(lane >> 4) * 128 + wr * 64 + m * 16 + (lane & 15)]; \
        _Pragma("unroll") \
        for (int n = 0; n < 2; ++n) \
            bfr[n] = (Bs_)[(lane >> 4) * 64 + wc * 32 + n * 16 + (lane & 15)]; \
        _Pragma("unroll") \
        for (int m = 0; m < 4; ++m) \
            _Pragma("unroll") \
            for (int n = 0; n < 2; ++n) \
                acc[m][n] = __builtin_amdgcn_mfma_f32_16x16x32_bf16(af[m], bfr[n], acc[m][n], 0, 0, 0); \
    } while (0)

    f32x4 acc[4][2];
    #pragma unroll
    for (int m = 0; m < 4; ++m)
        #pragma unroll
        for (int n = 0; n < 2; ++n)
            acc[m][n] = (f32x4){0.f, 0.f, 0.f, 0.f};

    // prologue: k-chunk 0 into buf0
    STAGE(A0, B0);
    __syncthreads();
    // 16 K-steps as 8 static pairs: stage-ahead overlaps MFMA, 1 barrier/step
    #pragma unroll
    for (int p = 0; p < 8; ++p) {
        STAGE(A1, B1);                   // k-chunk 2p+1 in flight
        COMPUTE(A0, B0);                 // k-chunk 2p
        __syncthreads();
        if (p < 7) STAGE(A0, B0);        // k-chunk 2p+2 in flight
        COMPUTE(A1, B1);                 // k-chunk 2p+1
        __syncthreads();
    }
#undef STAGE
#undef COMPUTE

    // epilogue: scale rows by dinv, bounce C-tile through LDS (row stride 72
    // u16 breaks write conflicts), then coalesced u16x8 stores.
    unsigned short* cs = (unsigned short*)smem;
    #pragma unroll
    for (int m = 0; m < 4; ++m) {
        int r = wr * 64 + m * 16 + (lane >> 4) * 4;
        float4 dv4 = *(const float4*)(dinv + row0 + r);
        float dvr[4] = {dv4.x, dv4.y, dv4.z, dv4.w};
        #pragma unroll
        for (int n = 0; n < 2; ++n) {
            int col = wc * 32 + n * 16 + (lane & 15);
            f32x4 v = acc[m][n];
            #pragma unroll
            for (int i = 0; i < 4; ++i)
                cs[(r + i) * 72 + col] = f2bf(v[i] * dvr[i]);
        }
    }
    __syncthreads();
    #pragma unroll
    for (int rr = 0; rr < 4; ++rr) {
        int row = rr * 32 + (tid >> 3);
        int col = (tid & 7) * 8;
        u16x8 vv = *(const u16x8*)(cs + row * 72 + col);
        *(u16x8*)(C + (size_t)(row0 + row) * DD + col0 + col) = vv;
    }
}

// ---------------------------------------------------------------------------
// column-split aggregation on pre-scaled h' = h*dinv:
//   out[v, cc] = maybe_relu( dv * (sum_{s->v} h'[s,cc] + h'[v,cc]) + b )
// NO per-edge dinv loads (fused into the GEMM epilogue) -> pure gather+add.
// Structure otherwise identical to the R4-proven body (template<RELU> only;
// do NOT add epilogue variants — R5/R6/R8 fused variants got serialized-gather
// codegen, 5-18x slower). Grid = 625*8; combo = bid&7 = (graph<<2)|colchunk
// pins each (graph, 128-col slice) to one XCD -> 2.56 MB fits per-XCD L2.
// Wave = 4 nodes x 16 lanes (ushort8 = 128 cols); edge loop unrolled x4.
template <bool RELU>
__global__ __launch_bounds__(256) void k_aggc(const unsigned short* __restrict__ h,
                                              const int* __restrict__ adj,
                                              const int* __restrict__ offs,
                                              const float* __restrict__ dinv,
                                              const float* __restrict__ bias,
                                              unsigned short* __restrict__ out) {
    int bid = blockIdx.x;
    int combo = bid & 7;                 // -> XCD (perf heuristic only)
    int nb = bid >> 3;                   // 0..624
    int g = combo >> 2;
    int yc = combo & 3;
    int wid = threadIdx.x >> 6;
    int lane = threadIdx.x & 63;
    int sub = lane >> 4;                 // node within wave
    int li = lane & 15;                  // col lane
    int v = nb * 16 + wid * 4 + sub;     // 0..9999 (exact: 625*16 = 10000)
    int c = yc * 128 + li * 8;
    int gbase = g * NN;
    const int* o = offs + g * (NN + 1);
    int beg = o[v], end = o[v + 1];
    const int* a = adj + g * NE;
    float dv = dinv[gbase + v];
    const unsigned short* hb = h + c;

    u16x8 hv = *(const u16x8*)(hb + (size_t)(gbase + v) * DD);
    float acc[8];
    #pragma unroll
    for (int j = 0; j < 8; ++j) acc[j] = bf2f(hv[j]);   // self-loop term (h' pre-scaled)

    int e = beg;
    for (; e + 4 <= end; e += 4) {
        int s0 = a[e] + gbase, s1 = a[e + 1] + gbase;
        int s2 = a[e + 2] + gbase, s3 = a[e + 3] + gbase;
        u16x8 r0 = *(const u16x8*)(hb + (size_t)s0 * DD);
        u16x8 r1 = *(const u16x8*)(hb + (size_t)s1 * DD);
        u16x8 r2 = *(const u16x8*)(hb + (size_t)s2 * DD);
        u16x8 r3 = *(const u16x8*)(hb + (size_t)s3 * DD);
        #pragma unroll
        for (int j = 0; j < 8; ++j) {
            float t01 = bf2f(r0[j]) + bf2f(r1[j]);
            float t23 = bf2f(r2[j]) + bf2f(r3[j]);
            acc[j] += t01 + t23;
        }
    }
    for (; e < end; ++e) {
        int s = a[e] + gbase;
        u16x8 hs = *(const u16x8*)(hb + (size_t)s * DD);
        #pragma unroll
        for (int j = 0; j < 8; ++j) acc[j] += bf2f(hs[j]);
    }

    float4 b0 = ((const float4*)(bias + c))[0];
    float4 b1 = ((const float4*)(bias + c))[1];
    float bb[8] = {b0.x, b0.y, b0.z, b0.w, b1.x, b1.y, b1.z, b1.w};
    u16x8 ov;
    #pragma unroll
    for (int j = 0; j < 8; ++j) {
        float x = fmaf(acc[j], dv, bb[j]);
        if (RELU) x = fmaxf(x, 0.f);
        ov[j] = f2bf(x);
    }
    *(u16x8*)(out + (size_t)(gbase + v) * DD + c) = ov;
}

// ---------------------------------------------------------------------------
// column sums for the per-graph mean: 2 x 128 blocks, 4 waves row-interleaved,
// ushort8 loads (full row per wave-load), LDS cross-wave reduce, 1 atomic/col.
__global__ __launch_bounds__(256) void k_meanpart(const unsigned short* __restrict__ h,
                                                  float* __restrict__ u) {
    __shared__ float sm[4][DD];
    int g = blockIdx.y;
    int chunk = blockIdx.x;              // 0..127
    int wid = threadIdx.x >> 6;
    int lane = threadIdx.x & 63;
    int c = lane * 8;
    const int rows_per = (NN + 127) / 128;   // 79
    int r0 = chunk * rows_per;
    int r1 = min(r0 + rows_per, NN);
    float acc[8] = {0.f, 0.f, 0.f, 0.f, 0.f, 0.f, 0.f, 0.f};
    for (int r = r0 + wid; r < r1; r += 4) {
        u16x8 hv = *(const u16x8*)(h + (size_t)(g * NN + r) * DD + c);
        #pragma unroll
        for (int j = 0; j < 8; ++j) acc[j] += bf2f(hv[j]);
    }
    #pragma unroll
    for (int j = 0; j < 8; ++j) sm[wid][c + j] = acc[j];
    __syncthreads();
    if (wid == 0) {
        #pragma unroll
        for (int j = 0; j < 8; ++j) {
            float s = sm[0][c + j] + sm[1][c + j] + sm[2][c + j] + sm[3][c + j];
            atomicAdd(&u[g * DD + c + j], s);
        }
    }
}

// head part 1: hacc[t] += sum_k z[k] * Wf1[k][t], k split over 32 blocks x 32 k
__global__ void k_head1(const float* __restrict__ u, const float* __restrict__ Wf1,
                        float* __restrict__ hacc) {
    int t = threadIdx.x;                 // 512
    int kb = blockIdx.x;                 // 32 blocks x 32 k
    const float inv = 1.0f / (float)NN;
    float acc = 0.f;
    for (int k = kb * 32; k < kb * 32 + 32; ++k) {
        float z = u[k] * inv;
        acc = fmaf(z, Wf1[(size_t)k * DD + t], acc);
    }
    atomicAdd(&hacc[t], acc);
}

// head part 2: relu + dot + sigmoid
__global__ void k_head2(const float* __restrict__ hacc, const float* __restrict__ bf1,
                        const float* __restrict__ Wf2, const float* __restrict__ bf2,
                        float* __restrict__ outp) {
    __shared__ float red[DD];
    int t = threadIdx.x;                 // 512
    float hv = fmaxf(hacc[t] + bf1[t], 0.f);
    red[t] = hv * Wf2[t];
    __syncthreads();
    for (int s = DD / 2; s > 0; s >>= 1) {
        if (t < s) red[t] += red[t + s];
        __syncthreads();
    }
    if (t == 0) outp[0] = 1.f / (1.f + expf(-(red[0] + bf2[0])));
}

// ---------------------------------------------------------------------------
extern "C" void kernel_launch(void* const* d_in, const int* in_sizes, int n_in,
                              void* d_out, int out_size, void* d_ws, size_t ws_size,
                              hipStream_t stream) {
    const float* x1  = (const float*)d_in[0];
    const float* x2  = (const float*)d_in[1];
    const int*   e1  = (const int*)d_in[2];
    const int*   e2  = (const int*)d_in[3];
    const float* W1  = (const float*)d_in[4];
    const float* W2  = (const float*)d_in[5];
    const float* W3  = (const float*)d_in[6];
    const float* b1  = (const float*)d_in[7];
    const float* b2  = (const float*)d_in[8];
    const float* b3  = (const float*)d_in[9];
    const float* Wf1 = (const float*)d_in[10];
    const float* bf1 = (const float*)d_in[11];
    const float* Wf2 = (const float*)d_in[12];
    const float* bf2 = (const float*)d_in[13];
    float* outp = (float*)d_out;

    // workspace carve-up (16B-aligned chunks); zero-region contiguous at end.
    // dinv lives in the zeroed region padded to MPAD so GEMM tail rows scale
    // by 0.0 (defined, never read downstream).
    char* w = (char*)d_ws;
    unsigned short* xb = (unsigned short*)w; w += (size_t)MPAD * DD * 2;   // 20.6 MB
    unsigned short* hG = (unsigned short*)w; w += (size_t)MPAD * DD * 2;   // 20.6 MB
    unsigned short* hA = (unsigned short*)w; w += (size_t)MPAD * DD * 2;   // 20.6 MB
    unsigned short* Wt = (unsigned short*)w; w += (size_t)3 * DD * DD * 2; // 1.5 MB
    int*   adj    = (int*)w;   w += 2 * NE * 4;
    int*   offs   = (int*)w;   w += 2 * (NN + 1) * 4 + 8;   // pad -> 16B
    char*  zbase  = w;                       // ---- zeroed region ----
    float* dinv   = (float*)w; w += (size_t)MPAD * 4;
    int*   cnt    = (int*)w;   w += 2 * NN * 4;
    int*   cursor = (int*)w;   w += 2 * NN * 4;
    float* u      = (float*)w; w += 2 * DD * 4;
    float* hacc   = (float*)w; w += DD * 4;
    size_t zeroBytes = (size_t)(w - zbase);

    // preprocessing: memset, then one fused dispatch (count | cvt_x | cvt_w)
    hipMemsetAsync(zbase, 0, zeroBytes, stream);
    k_pre<<<NB_CVTX + NB_CNT + NB_CVTW, 256, 0, stream>>>(x1, x2, xb, e1, e2, cnt,
                                                          W1, W2, W3, Wt);
    k_scan<<<2, 1024, 0, stream>>>(cnt, offs, dinv);
    k_fill<<<(2 * NE + 255) / 256, 256, 0, stream>>>(e1, e2, offs, cursor, adj);

    const int ggrid = (MPAD / 128) * (DD / 64);    // 1256
    const int aggGrid = (NN / 16) * 8;             // 5000

    // layer 1
    k_gemm<<<ggrid, 256, 0, stream>>>(xb, Wt, dinv, hG);
    k_aggc<true><<<aggGrid, 256, 0, stream>>>(hG, adj, offs, dinv, b1, hA);
    // layer 2
    k_gemm<<<ggrid, 256, 0, stream>>>(hA, Wt + (size_t)DD * DD, dinv, hG);
    k_aggc<true><<<aggGrid, 256, 0, stream>>>(hG, adj, offs, dinv, b2, hA);
    // layer 3
    k_gemm<<<ggrid, 256, 0, stream>>>(hA, Wt + (size_t)2 * DD * DD, dinv, hG);
    k_aggc<false><<<aggGrid, 256, 0, stream>>>(hG, adj, offs, dinv, b3, hA);

    // mean + head
    k_meanpart<<<dim3(128, 2), 256, 0, stream>>>(hA, u);
    k_head1<<<32, DD, 0, stream>>>(u, Wf1, hacc);
    k_head2<<<1, DD, 0, stream>>>(hacc, bf1, Wf2, bf2, outp);
}

// Round 14
// 266.025 us; speedup vs baseline: 1.0474x; 1.0474x over previous
//
#include <hip/hip_runtime.h>
#include <math.h>

#define NN 10000       // nodes per graph
#define NE 160000      // edges per graph
#define DD 512         // feature dim
#define MPAD 20096     // 157 * 128 rows (padded batched M)

typedef __attribute__((ext_vector_type(8))) short bf16x8;
typedef __attribute__((ext_vector_type(4))) float f32x4;
typedef __attribute__((ext_vector_type(8))) unsigned short u16x8;

__device__ __forceinline__ unsigned short f2bf(float f) {
    unsigned u = __float_as_uint(f);
    u += 0x7FFFu + ((u >> 16) & 1u);          // round-to-nearest-even
    return (unsigned short)(u >> 16);
}
__device__ __forceinline__ float bf2f(unsigned short h) {
    return __uint_as_float(((unsigned)h) << 16);
}

// async global->LDS, 16B per lane; LDS dest is wave-uniform base + lane*16
#define GLOAD16(g, l) __builtin_amdgcn_global_load_lds( \
    (const __attribute__((address_space(1))) void*)(unsigned long long)(const void*)(g), \
    (__attribute__((address_space(3))) void*)(unsigned)(unsigned long long)(void*)(l), \
    16, 0, 0)

// ---------------------------------------------------------------------------
// fused preprocessing: [0,5024) cvt_x | [5024,6274) count | [6274,9346) cvt_w
// (the three are mutually independent; one dispatch overlaps them)
#define NB_CVTX 5024   // MPAD*DD/8/256
#define NB_CNT  1250   // 2*NE/256
#define NB_CVTW 3072   // (DD/16)*(DD/16)*3
__global__ __launch_bounds__(256) void k_pre(const float* __restrict__ x1,
                                             const float* __restrict__ x2,
                                             unsigned short* __restrict__ xb,
                                             const int* __restrict__ e1,
                                             const int* __restrict__ e2,
                                             int* __restrict__ cnt,
                                             const float* __restrict__ W1,
                                             const float* __restrict__ W2,
                                             const float* __restrict__ W3,
                                             unsigned short* __restrict__ Wt) {
    int bid = blockIdx.x;
    int tid = threadIdx.x;
    if (bid < NB_CVTX) {
        // ---- fp32 -> bf16 convert of node features, tail rows zeroed ----
        long long i8 = ((long long)bid * 256 + tid) * 8;
        int row = (int)(i8 >> 9);
        int col = (int)(i8 & 511);
        u16x8 ov;
        if (row < 2 * NN) {
            const float* src = (row < NN) ? (x1 + (size_t)row * DD + col)
                                          : (x2 + (size_t)(row - NN) * DD + col);
            float4 f0 = ((const float4*)src)[0];
            float4 f1 = ((const float4*)src)[1];
            ov[0] = f2bf(f0.x); ov[1] = f2bf(f0.y); ov[2] = f2bf(f0.z); ov[3] = f2bf(f0.w);
            ov[4] = f2bf(f1.x); ov[5] = f2bf(f1.y); ov[6] = f2bf(f1.z); ov[7] = f2bf(f1.w);
        } else {
            #pragma unroll
            for (int j = 0; j < 8; ++j) ov[j] = 0;
        }
        *(u16x8*)(xb + i8) = ov;
    } else if (bid < NB_CVTX + NB_CNT) {
        // ---- in-degree count (self-loop handled as +1 later) ----
        int i = (bid - NB_CVTX) * 256 + tid;
        if (i < NE) {
            atomicAdd(&cnt[e1[NE + i]], 1);
        } else {
            int e = i - NE;
            atomicAdd(&cnt[NN + e2[NE + e]], 1);
        }
    } else {
        // ---- W[k][n] fp32 -> Wt[n][k] bf16, 16x16 tiles, 256 threads ----
        __shared__ float t[16][17];
        int b2 = bid - NB_CVTX - NB_CNT;
        int z = b2 >> 10;                 // 0..2
        int rem = b2 & 1023;
        int n0 = (rem & 31) * 16;
        int k0 = (rem >> 5) * 16;
        const float* W = (z == 0) ? W1 : (z == 1) ? W2 : W3;
        unsigned short* o = Wt + (size_t)z * DD * DD;
        int tx = tid & 15, ty = tid >> 4;
        t[ty][tx] = W[(size_t)(k0 + ty) * DD + n0 + tx];
        __syncthreads();
        o[(size_t)(n0 + ty) * DD + k0 + tx] = f2bf(t[tx][ty]);
    }
}

// exclusive scan of per-node edge counts -> CSR offsets; also emits dinv.
// One block per graph.
__global__ void k_scan(const int* cnt, int* offs, float* dinv) {
    int g = blockIdx.x;
    const int* c = cnt + g * NN;
    int* o = offs + g * (NN + 1);
    __shared__ int sums[1024];
    int t = threadIdx.x;                  // 1024 threads
    const int PER = 10;                   // 1024*10 >= NN
    int base = t * PER;
    int vals[PER];
    int local = 0;
    #pragma unroll
    for (int j = 0; j < PER; ++j) {
        int idx = base + j;
        int v = (idx < NN) ? c[idx] : 0;
        vals[j] = v; local += v;
        if (idx < NN) dinv[g * NN + idx] = rsqrtf((float)(v + 1));
    }
    sums[t] = local;
    __syncthreads();
    for (int off = 1; off < 1024; off <<= 1) {
        int v = (t >= off) ? sums[t - off] : 0;
        __syncthreads();
        sums[t] += v;
        __syncthreads();
    }
    int prefix = (t > 0) ? sums[t - 1] : 0;   // exclusive
    #pragma unroll
    for (int j = 0; j < PER; ++j) {
        int idx = base + j;
        if (idx < NN) { o[idx] = prefix; prefix += vals[j]; }
    }
    if (t == 1023) o[NN] = sums[1023];
}

// scatter edges into CSR buckets (adj holds SRC node per incoming edge of dst)
__global__ void k_fill(const int* e1, const int* e2, const int* offs,
                       int* cursor, int* adj) {
    int i = blockIdx.x * blockDim.x + threadIdx.x;
    if (i >= 2 * NE) return;
    int g = (i < NE) ? 0 : 1;
    int e = i - g * NE;
    const int* ei = g ? e2 : e1;
    int s = ei[e];
    int d = ei[NE + e];
    int pos = atomicAdd(&cursor[g * NN + d], 1);
    adj[g * NE + offs[g * (NN + 1) + d] + pos] = s;
}

// ---------------------------------------------------------------------------
// bf16 MFMA GEMM: C[MPAD x 512] = dinv[row] * (A[MPAD x 512] * W^T).
// R11-proven configuration (best: 266 us total). 128x128 tile, 4 waves (2x2),
// 16x16x32 MFMA, global_load_lds width-16. T3 2-phase pipeline: BK=32
// double-buffered LDS (4x8KB), STAGE(next) issued BEFORE COMPUTE(cur), ONE
// barrier per K-step. Static buffer names (rule #20). Epilogue: dinv scale,
// LDS bounce (stride-136 u16), coalesced u16x8 stores. Bijective XCD swizzle.
// NOTE: R12 (8 waves/block) and R13 (128x64 tile) both REGRESSED vs this —
// intra-block waves share the barrier (no extra TLP), smaller tiles worsen
// staged-bytes/FLOP. This shape (N=K=512) is latency-bound at ~27 us/dispatch.
__global__ __launch_bounds__(256) void k_gemm(const unsigned short* __restrict__ A,
                                              const unsigned short* __restrict__ Bt,
                                              const float* __restrict__ dinv,
                                              unsigned short* __restrict__ C) {
    __shared__ char smem[34816];          // 4x8KB dbuf tiles; 34KB C-bounce
    bf16x8* A0 = (bf16x8*)smem;
    bf16x8* B0 = (bf16x8*)(smem + 8192);
    bf16x8* A1 = (bf16x8*)(smem + 16384);
    bf16x8* B1 = (bf16x8*)(smem + 24576);

    int tid = threadIdx.x;
    int lane = tid & 63;
    int wid = tid >> 6;
    int wr = wid >> 1, wc = wid & 1;

    int b = blockIdx.x;                      // 0..627
    int xcd = b & 7;
    int idx = b >> 3;
    int start = (xcd < 4) ? xcd * 79 : 316 + (xcd - 4) * 78;
    int gi = start + idx;                    // bijective over [0,628)
    int rp = gi >> 2, cb = gi & 3;
    int row0 = rp * 128, col0 = cb * 128;

    // staging streams: chunk ch covers row (ch&127), k-bytes (ch>>7)*8
    int ch0 = wid * 64 + lane;
    int ch1 = 256 + wid * 64 + lane;
    const unsigned short* gA0 = A + (size_t)(row0 + (ch0 & 127)) * DD + (ch0 >> 7) * 8;
    const unsigned short* gA1 = A + (size_t)(row0 + (ch1 & 127)) * DD + (ch1 >> 7) * 8;
    const unsigned short* gB0 = Bt + (size_t)(col0 + (ch0 & 127)) * DD + (ch0 >> 7) * 8;
    const unsigned short* gB1 = Bt + (size_t)(col0 + (ch1 & 127)) * DD + (ch1 >> 7) * 8;

#define STAGE(Ad, Bd) do { \
        GLOAD16(gA0, (Ad) + wid * 64); \
        GLOAD16(gA1, (Ad) + 256 + wid * 64); \
        GLOAD16(gB0, (Bd) + wid * 64); \
        GLOAD16(gB1, (Bd) + 256 + wid * 64); \
        gA0 += 32; gA1 += 32; gB0 += 32; gB1 += 32; \
    } while (0)

#define COMPUTE(As_, Bs_) do { \
        bf16x8 af[4], bfr[4]; \
        _Pragma("unroll") \
        for (int m = 0; m < 4; ++m) { \
            af[m]  = (As_)[(lane >> 4) * 128 + wr * 64 + m * 16 + (lane & 15)]; \
            bfr[m] = (Bs_)[(lane >> 4) * 128 + wc * 64 + m * 16 + (lane & 15)]; \
        } \
        _Pragma("unroll") \
        for (int m = 0; m < 4; ++m) \
            _Pragma("unroll") \
            for (int n = 0; n < 4; ++n) \
                acc[m][n] = __builtin_amdgcn_mfma_f32_16x16x32_bf16(af[m], bfr[n], acc[m][n], 0, 0, 0); \
    } while (0)

    f32x4 acc[4][4];
    #pragma unroll
    for (int m = 0; m < 4; ++m)
        #pragma unroll
        for (int n = 0; n < 4; ++n)
            acc[m][n] = (f32x4){0.f, 0.f, 0.f, 0.f};

    // prologue: k-chunk 0 into buf0
    STAGE(A0, B0);
    __syncthreads();
    // 16 K-steps as 8 static pairs: stage-ahead overlaps MFMA, 1 barrier/step
    #pragma unroll
    for (int p = 0; p < 8; ++p) {
        STAGE(A1, B1);                   // k-chunk 2p+1 in flight
        COMPUTE(A0, B0);                 // k-chunk 2p
        __syncthreads();
        if (p < 7) STAGE(A0, B0);        // k-chunk 2p+2 in flight
        COMPUTE(A1, B1);                 // k-chunk 2p+1
        __syncthreads();
    }
#undef STAGE
#undef COMPUTE

    // epilogue: scale rows by dinv, bounce C-tile through LDS (row stride 136
    // u16 breaks write conflicts), then 8 coalesced u16x8 stores per thread.
    unsigned short* cs = (unsigned short*)smem;
    #pragma unroll
    for (int m = 0; m < 4; ++m) {
        int r = wr * 64 + m * 16 + (lane >> 4) * 4;
        float4 dv4 = *(const float4*)(dinv + row0 + r);
        float dvr[4] = {dv4.x, dv4.y, dv4.z, dv4.w};
        #pragma unroll
        for (int n = 0; n < 4; ++n) {
            int col = wc * 64 + n * 16 + (lane & 15);
            f32x4 v = acc[m][n];
            #pragma unroll
            for (int i = 0; i < 4; ++i)
                cs[(r + i) * 136 + col] = f2bf(v[i] * dvr[i]);
        }
    }
    __syncthreads();
    #pragma unroll
    for (int rr = 0; rr < 8; ++rr) {
        int row = rr * 16 + (tid >> 4);
        int col = (tid & 15) * 8;
        u16x8 vv = *(const u16x8*)(cs + row * 136 + col);
        *(u16x8*)(C + (size_t)(row0 + row) * DD + col0 + col) = vv;
    }
}

// ---------------------------------------------------------------------------
// column-split aggregation on pre-scaled h' = h*dinv:
//   out[v, cc] = maybe_relu( dv * (sum_{s->v} h'[s,cc] + h'[v,cc]) + b )
// NO per-edge dinv loads (fused into the GEMM epilogue) -> pure gather+add.
// Structure otherwise identical to the R4-proven body (template<RELU> only;
// do NOT add epilogue variants — R5/R6/R8 fused variants got serialized-gather
// codegen, 5-18x slower). Grid = 625*8; combo = bid&7 = (graph<<2)|colchunk
// pins each (graph, 128-col slice) to one XCD -> 2.56 MB fits per-XCD L2.
// Wave = 4 nodes x 16 lanes (ushort8 = 128 cols); edge loop unrolled x4.
template <bool RELU>
__global__ __launch_bounds__(256) void k_aggc(const unsigned short* __restrict__ h,
                                              const int* __restrict__ adj,
                                              const int* __restrict__ offs,
                                              const float* __restrict__ dinv,
                                              const float* __restrict__ bias,
                                              unsigned short* __restrict__ out) {
    int bid = blockIdx.x;
    int combo = bid & 7;                 // -> XCD (perf heuristic only)
    int nb = bid >> 3;                   // 0..624
    int g = combo >> 2;
    int yc = combo & 3;
    int wid = threadIdx.x >> 6;
    int lane = threadIdx.x & 63;
    int sub = lane >> 4;                 // node within wave
    int li = lane & 15;                  // col lane
    int v = nb * 16 + wid * 4 + sub;     // 0..9999 (exact: 625*16 = 10000)
    int c = yc * 128 + li * 8;
    int gbase = g * NN;
    const int* o = offs + g * (NN + 1);
    int beg = o[v], end = o[v + 1];
    const int* a = adj + g * NE;
    float dv = dinv[gbase + v];
    const unsigned short* hb = h + c;

    u16x8 hv = *(const u16x8*)(hb + (size_t)(gbase + v) * DD);
    float acc[8];
    #pragma unroll
    for (int j = 0; j < 8; ++j) acc[j] = bf2f(hv[j]);   // self-loop term (h' pre-scaled)

    int e = beg;
    for (; e + 4 <= end; e += 4) {
        int s0 = a[e] + gbase, s1 = a[e + 1] + gbase;
        int s2 = a[e + 2] + gbase, s3 = a[e + 3] + gbase;
        u16x8 r0 = *(const u16x8*)(hb + (size_t)s0 * DD);
        u16x8 r1 = *(const u16x8*)(hb + (size_t)s1 * DD);
        u16x8 r2 = *(const u16x8*)(hb + (size_t)s2 * DD);
        u16x8 r3 = *(const u16x8*)(hb + (size_t)s3 * DD);
        #pragma unroll
        for (int j = 0; j < 8; ++j) {
            float t01 = bf2f(r0[j]) + bf2f(r1[j]);
            float t23 = bf2f(r2[j]) + bf2f(r3[j]);
            acc[j] += t01 + t23;
        }
    }
    for (; e < end; ++e) {
        int s = a[e] + gbase;
        u16x8 hs = *(const u16x8*)(hb + (size_t)s * DD);
        #pragma unroll
        for (int j = 0; j < 8; ++j) acc[j] += bf2f(hs[j]);
    }

    float4 b0 = ((const float4*)(bias + c))[0];
    float4 b1 = ((const float4*)(bias + c))[1];
    float bb[8] = {b0.x, b0.y, b0.z, b0.w, b1.x, b1.y, b1.z, b1.w};
    u16x8 ov;
    #pragma unroll
    for (int j = 0; j < 8; ++j) {
        float x = fmaf(acc[j], dv, bb[j]);
        if (RELU) x = fmaxf(x, 0.f);
        ov[j] = f2bf(x);
    }
    *(u16x8*)(out + (size_t)(gbase + v) * DD + c) = ov;
}

// ---------------------------------------------------------------------------
// column sums for the per-graph mean: 2 x 128 blocks, 4 waves row-interleaved,
// ushort8 loads (full row per wave-load), LDS cross-wave reduce, 1 atomic/col.
__global__ __launch_bounds__(256) void k_meanpart(const unsigned short* __restrict__ h,
                                                  float* __restrict__ u) {
    __shared__ float sm[4][DD];
    int g = blockIdx.y;
    int chunk = blockIdx.x;              // 0..127
    int wid = threadIdx.x >> 6;
    int lane = threadIdx.x & 63;
    int c = lane * 8;
    const int rows_per = (NN + 127) / 128;   // 79
    int r0 = chunk * rows_per;
    int r1 = min(r0 + rows_per, NN);
    float acc[8] = {0.f, 0.f, 0.f, 0.f, 0.f, 0.f, 0.f, 0.f};
    for (int r = r0 + wid; r < r1; r += 4) {
        u16x8 hv = *(const u16x8*)(h + (size_t)(g * NN + r) * DD + c);
        #pragma unroll
        for (int j = 0; j < 8; ++j) acc[j] += bf2f(hv[j]);
    }
    #pragma unroll
    for (int j = 0; j < 8; ++j) sm[wid][c + j] = acc[j];
    __syncthreads();
    if (wid == 0) {
        #pragma unroll
        for (int j = 0; j < 8; ++j) {
            float s = sm[0][c + j] + sm[1][c + j] + sm[2][c + j] + sm[3][c + j];
            atomicAdd(&u[g * DD + c + j], s);
        }
    }
}

// head part 1: hacc[t] += sum_k z[k] * Wf1[k][t], k split over 32 blocks x 32 k
__global__ void k_head1(const float* __restrict__ u, const float* __restrict__ Wf1,
                        float* __restrict__ hacc) {
    int t = threadIdx.x;                 // 512
    int kb = blockIdx.x;                 // 32 blocks x 32 k
    const float inv = 1.0f / (float)NN;
    float acc = 0.f;
    for (int k = kb * 32; k < kb * 32 + 32; ++k) {
        float z = u[k] * inv;
        acc = fmaf(z, Wf1[(size_t)k * DD + t], acc);
    }
    atomicAdd(&hacc[t], acc);
}

// head part 2: relu + dot + sigmoid
__global__ void k_head2(const float* __restrict__ hacc, const float* __restrict__ bf1,
                        const float* __restrict__ Wf2, const float* __restrict__ bf2,
                        float* __restrict__ outp) {
    __shared__ float red[DD];
    int t = threadIdx.x;                 // 512
    float hv = fmaxf(hacc[t] + bf1[t], 0.f);
    red[t] = hv * Wf2[t];
    __syncthreads();
    for (int s = DD / 2; s > 0; s >>= 1) {
        if (t < s) red[t] += red[t + s];
        __syncthreads();
    }
    if (t == 0) outp[0] = 1.f / (1.f + expf(-(red[0] + bf2[0])));
}

// ---------------------------------------------------------------------------
extern "C" void kernel_launch(void* const* d_in, const int* in_sizes, int n_in,
                              void* d_out, int out_size, void* d_ws, size_t ws_size,
                              hipStream_t stream) {
    const float* x1  = (const float*)d_in[0];
    const float* x2  = (const float*)d_in[1];
    const int*   e1  = (const int*)d_in[2];
    const int*   e2  = (const int*)d_in[3];
    const float* W1  = (const float*)d_in[4];
    const float* W2  = (const float*)d_in[5];
    const float* W3  = (const float*)d_in[6];
    const float* b1  = (const float*)d_in[7];
    const float* b2  = (const float*)d_in[8];
    const float* b3  = (const float*)d_in[9];
    const float* Wf1 = (const float*)d_in[10];
    const float* bf1 = (const float*)d_in[11];
    const float* Wf2 = (const float*)d_in[12];
    const float* bf2 = (const float*)d_in[13];
    float* outp = (float*)d_out;

    // workspace carve-up (16B-aligned chunks); zero-region contiguous at end.
    // dinv lives in the zeroed region padded to MPAD so GEMM tail rows scale
    // by 0.0 (defined, never read downstream).
    char* w = (char*)d_ws;
    unsigned short* xb = (unsigned short*)w; w += (size_t)MPAD * DD * 2;   // 20.6 MB
    unsigned short* hG = (unsigned short*)w; w += (size_t)MPAD * DD * 2;   // 20.6 MB
    unsigned short* hA = (unsigned short*)w; w += (size_t)MPAD * DD * 2;   // 20.6 MB
    unsigned short* Wt = (unsigned short*)w; w += (size_t)3 * DD * DD * 2; // 1.5 MB
    int*   adj    = (int*)w;   w += 2 * NE * 4;
    int*   offs   = (int*)w;   w += 2 * (NN + 1) * 4 + 8;   // pad -> 16B
    char*  zbase  = w;                       // ---- zeroed region ----
    float* dinv   = (float*)w; w += (size_t)MPAD * 4;
    int*   cnt    = (int*)w;   w += 2 * NN * 4;
    int*   cursor = (int*)w;   w += 2 * NN * 4;
    float* u      = (float*)w; w += 2 * DD * 4;
    float* hacc   = (float*)w; w += DD * 4;
    size_t zeroBytes = (size_t)(w - zbase);

    // preprocessing: memset, then one fused dispatch (count | cvt_x | cvt_w)
    hipMemsetAsync(zbase, 0, zeroBytes, stream);
    k_pre<<<NB_CVTX + NB_CNT + NB_CVTW, 256, 0, stream>>>(x1, x2, xb, e1, e2, cnt,
                                                          W1, W2, W3, Wt);
    k_scan<<<2, 1024, 0, stream>>>(cnt, offs, dinv);
    k_fill<<<(2 * NE + 255) / 256, 256, 0, stream>>>(e1, e2, offs, cursor, adj);

    const int ggrid = (MPAD / 128) * (DD / 128);   // 628
    const int aggGrid = (NN / 16) * 8;             // 5000

    // layer 1
    k_gemm<<<ggrid, 256, 0, stream>>>(xb, Wt, dinv, hG);
    k_aggc<true><<<aggGrid, 256, 0, stream>>>(hG, adj, offs, dinv, b1, hA);
    // layer 2
    k_gemm<<<ggrid, 256, 0, stream>>>(hA, Wt + (size_t)DD * DD, dinv, hG);
    k_aggc<true><<<aggGrid, 256, 0, stream>>>(hG, adj, offs, dinv, b2, hA);
    // layer 3
    k_gemm<<<ggrid, 256, 0, stream>>>(hA, Wt + (size_t)2 * DD * DD, dinv, hG);
    k_aggc<false><<<aggGrid, 256, 0, stream>>>(hG, adj, offs, dinv, b3, hA);

    // mean + head
    k_meanpart<<<dim3(128, 2), 256, 0, stream>>>(hA, u);
    k_head1<<<32, DD, 0, stream>>>(u, Wf1, hacc);
    k_head2<<<1, DD, 0, stream>>>(hacc, bf1, Wf2, bf2, outp);
}